// Round 14
// baseline (72.238 us; speedup 1.0000x reference)
//
#include <hip/hip_runtime.h>
#include <stdint.h>

typedef __attribute__((ext_vector_type(8))) __bf16 bf16x8;
typedef __attribute__((ext_vector_type(4))) float f32x4;

__device__ __forceinline__ unsigned short f2bf(float f) {
  union { float f; unsigned int u; } v; v.f = f;
  unsigned int u = v.u;
  return (unsigned short)((u + 0x7fffu + ((u >> 16) & 1u)) >> 16);
}
__device__ __forceinline__ float bf2f(unsigned int hw) {
  union { unsigned int u; float f; } v; v.u = hw << 16;
  return v.f;
}

__device__ __forceinline__ void async_copy16(const void* g, void* s) {
  __builtin_amdgcn_global_load_lds(
      (__attribute__((address_space(1))) void*)const_cast<void*>(g),
      (__attribute__((address_space(3))) void*)s,
      16, 0, 0);
}

// ---------------- W fp32 -> bf16 (already [N=768][K=768] row-major) --------
__global__ __launch_bounds__(256) void convw_kernel(const float* __restrict__ W,
                                                    unsigned short* __restrict__ Wb) {
  int i = blockIdx.x * 256 + threadIdx.x;  // 147456 threads x 4 floats
  float4 v = ((const float4*)W)[i];
  uint2 o;
  o.x = (unsigned int)f2bf(v.x) | ((unsigned int)f2bf(v.y) << 16);
  o.y = (unsigned int)f2bf(v.z) | ((unsigned int)f2bf(v.w) << 16);
  ((uint2*)Wb)[i] = o;
}

// A-layout helper: coefficient-array (y,x) -> A[mrow][k] patch layout
__device__ __forceinline__ size_t aidx(int bc_b, int c, int y, int xx) {
  int mrow = bc_b * 196 + (y >> 4) * 14 + (xx >> 4);
  int k = c * 256 + (y & 15) * 16 + (xx & 15);
  return (size_t)mrow * 768 + (size_t)k;
}

__device__ __forceinline__ uint4 pack8(const float* v) {
  uint4 o;
  o.x = (unsigned int)f2bf(v[0]) | ((unsigned int)f2bf(v[1]) << 16);
  o.y = (unsigned int)f2bf(v[2]) | ((unsigned int)f2bf(v[3]) << 16);
  o.z = (unsigned int)f2bf(v[4]) | ((unsigned int)f2bf(v[5]) << 16);
  o.w = (unsigned int)f2bf(v[6]) | ((unsigned int)f2bf(v[7]) << 16);
  return o;
}

// ---- DWT level 1: thread = one row-pair x 16-col strip of one (b,c) ------
// Produces 8 consecutive coeffs of cH1/cV1/cD1 (16B stores into A) and
// 8 of cA1 (16B bf16 store into scratch). All stores 16B-aligned, one patch.
__global__ __launch_bounds__(256) void dwt1_kernel(const float* __restrict__ x,
                                                   unsigned short* __restrict__ A,
                                                   unsigned short* __restrict__ sc) {
  int tid = blockIdx.x * 256 + threadIdx.x;  // 384*112*14 = 602112
  int s = tid % 14;
  int r = tid / 14;
  int I = r % 112;
  int t = r / 112;  // b*3 + c
  int c = t % 3;
  int b = t / 3;

  const float* xp = x + ((size_t)t * 224 + 2 * I) * 224 + 16 * s;
  float4 q0 = ((const float4*)xp)[0], q1 = ((const float4*)xp)[1];
  float4 q2 = ((const float4*)xp)[2], q3 = ((const float4*)xp)[3];
  const float* xq = xp + 224;
  float4 p0 = ((const float4*)xq)[0], p1 = ((const float4*)xq)[1];
  float4 p2 = ((const float4*)xq)[2], p3 = ((const float4*)xq)[3];

  float r0[16] = {q0.x, q0.y, q0.z, q0.w, q1.x, q1.y, q1.z, q1.w,
                  q2.x, q2.y, q2.z, q2.w, q3.x, q3.y, q3.z, q3.w};
  float r1[16] = {p0.x, p0.y, p0.z, p0.w, p1.x, p1.y, p1.z, p1.w,
                  p2.x, p2.y, p2.z, p2.w, p3.x, p3.y, p3.z, p3.w};

  float A1[8], H[8], V[8], D[8];
#pragma unroll
  for (int p = 0; p < 8; ++p) {
    float a = r0[2 * p], bb = r0[2 * p + 1], cc = r1[2 * p], dd = r1[2 * p + 1];
    A1[p] = 0.5f * ((a + bb) + (cc + dd));
    H[p]  = 0.5f * ((a + bb) - (cc + dd));
    V[p]  = 0.5f * ((a - bb) + (cc - dd));
    D[p]  = 0.5f * ((a - bb) - (cc - dd));
  }

  int xx = 8 * s;
  *(uint4*)(A + aidx(b, c, I, 112 + xx))       = pack8(H);
  *(uint4*)(A + aidx(b, c, 112 + I, xx))       = pack8(V);
  *(uint4*)(A + aidx(b, c, 112 + I, 112 + xx)) = pack8(D);
  *(uint4*)(sc + ((size_t)t * 112 + I) * 112 + xx) = pack8(A1);
}

// ---- DWT level 2: consumes bf16 cA1 scratch, writes 4 lvl2 bands ---------
__global__ __launch_bounds__(256) void dwt2_kernel(const unsigned short* __restrict__ sc,
                                                   unsigned short* __restrict__ A) {
  int tid = blockIdx.x * 256 + threadIdx.x;  // 384*56*7 = 150528
  int s = tid % 7;
  int r = tid / 7;
  int I = r % 56;
  int t = r / 56;  // b*3 + c
  int c = t % 3;
  int b = t / 3;

  const unsigned short* sp = sc + ((size_t)t * 112 + 2 * I) * 112 + 16 * s;
  uint4 a0 = *(const uint4*)sp, a1 = *(const uint4*)(sp + 8);
  uint4 b0 = *(const uint4*)(sp + 112), b1 = *(const uint4*)(sp + 120);

  float r0[16] = {bf2f(a0.x & 0xffff), bf2f(a0.x >> 16), bf2f(a0.y & 0xffff), bf2f(a0.y >> 16),
                  bf2f(a0.z & 0xffff), bf2f(a0.z >> 16), bf2f(a0.w & 0xffff), bf2f(a0.w >> 16),
                  bf2f(a1.x & 0xffff), bf2f(a1.x >> 16), bf2f(a1.y & 0xffff), bf2f(a1.y >> 16),
                  bf2f(a1.z & 0xffff), bf2f(a1.z >> 16), bf2f(a1.w & 0xffff), bf2f(a1.w >> 16)};
  float r1[16] = {bf2f(b0.x & 0xffff), bf2f(b0.x >> 16), bf2f(b0.y & 0xffff), bf2f(b0.y >> 16),
                  bf2f(b0.z & 0xffff), bf2f(b0.z >> 16), bf2f(b0.w & 0xffff), bf2f(b0.w >> 16),
                  bf2f(b1.x & 0xffff), bf2f(b1.x >> 16), bf2f(b1.y & 0xffff), bf2f(b1.y >> 16),
                  bf2f(b1.z & 0xffff), bf2f(b1.z >> 16), bf2f(b1.w & 0xffff), bf2f(b1.w >> 16)};

  float A2[8], H2[8], V2[8], D2[8];
#pragma unroll
  for (int p = 0; p < 8; ++p) {
    float a = r0[2 * p], bb = r0[2 * p + 1], cc = r1[2 * p], dd = r1[2 * p + 1];
    A2[p] = 0.5f * ((a + bb) + (cc + dd));
    H2[p] = 0.5f * ((a + bb) - (cc + dd));
    V2[p] = 0.5f * ((a - bb) + (cc - dd));
    D2[p] = 0.5f * ((a - bb) - (cc - dd));
  }

  int xx = 8 * s;
  *(uint4*)(A + aidx(b, c, I, xx))           = pack8(A2);
  *(uint4*)(A + aidx(b, c, I, 56 + xx))      = pack8(H2);
  *(uint4*)(A + aidx(b, c, 56 + I, xx))      = pack8(V2);
  *(uint4*)(A + aidx(b, c, 56 + I, 56 + xx)) = pack8(D2);
}

// --------- bf16 MFMA GEMM (r13 exact): 128x192, BK=64, dbuf, 4 waves ------
__global__ __launch_bounds__(256) void gemm_kernel(const unsigned short* __restrict__ A,
                                                   const unsigned short* __restrict__ Bt,
                                                   const float* __restrict__ bias,
                                                   float* __restrict__ C) {
  constexpr int K = 768, N = 768;
  constexpr int NT = 12;  // K / 64
  __shared__ unsigned short As[2][128 * 64];  // 16 KB per buffer
  __shared__ unsigned short Bs[2][192 * 64];  // 24 KB per buffer

  const int orig = blockIdx.x;
  const int tile = (orig & 7) * 98 + (orig >> 3);
  const int bm = tile >> 2, bn = tile & 3;
  const int mbase = bm * 128, nbase = bn * 192;

  const int tid = threadIdx.x;
  const int lane = tid & 63;
  const int wave = tid >> 6;
  const int wr = wave >> 1, wc = wave & 1;  // wave tile 64x96

  f32x4 acc[4][6] = {};

  const int srow = wave * 8 + (lane >> 3);
  const int kcs = (lane & 7) ^ ((lane >> 3) & 7);
  const unsigned short* gA[4];
  const unsigned short* gB[6];
#pragma unroll
  for (int i = 0; i < 4; ++i) gA[i] = A + (size_t)(mbase + i * 32 + srow) * K + kcs * 8;
#pragma unroll
  for (int j = 0; j < 6; ++j) gB[j] = Bt + (size_t)(nbase + j * 32 + srow) * K + kcs * 8;

  auto stageA = [&](int buf, int kt) {
    char* sa = (char*)As + buf * 16384 + wave * 1024;
    const int ko = kt * 64;
#pragma unroll
    for (int i = 0; i < 4; ++i) async_copy16(gA[i] + ko, sa + i * 4096);
  };
  auto stageB = [&](int buf, int kt) {
    char* sb = (char*)Bs + buf * 24576 + wave * 1024;
    const int ko = kt * 64;
#pragma unroll
    for (int j = 0; j < 6; ++j) async_copy16(gB[j] + ko, sb + j * 4096);
  };

  const int fr = lane & 15;
  const int kq = lane >> 4;
  const int ch0 = ((0 * 4 + kq) ^ (fr & 7)) * 16;
  const int ch1 = ((1 * 4 + kq) ^ (fr & 7)) * 16;

  stageA(0, 0);
  stageB(0, 0);
  asm volatile("s_waitcnt vmcnt(0)" ::: "memory");
  __builtin_amdgcn_s_barrier();

#pragma unroll
  for (int kt = 0; kt < NT; ++kt) {
    const int cb = kt & 1;
    const char* pa = (const char*)As + cb * 16384 + (wr * 64 + fr) * 128;
    const char* pb = (const char*)Bs + cb * 24576 + (wc * 96 + fr) * 128;
    bf16x8 af[4], bv[6];

    if (kt + 1 < NT) stageA(cb ^ 1, kt + 1);
#pragma unroll
    for (int ni = 0; ni < 6; ++ni) bv[ni] = *(const bf16x8*)(pb + ni * 2048 + ch0);
#pragma unroll
    for (int mi = 0; mi < 4; ++mi) af[mi] = *(const bf16x8*)(pa + mi * 2048 + ch0);
    asm volatile("s_waitcnt lgkmcnt(0)" ::: "memory");
    __builtin_amdgcn_sched_barrier(0);
    __builtin_amdgcn_s_setprio(1);
#pragma unroll
    for (int mi = 0; mi < 4; ++mi)
#pragma unroll
      for (int ni = 0; ni < 6; ++ni)
        acc[mi][ni] = __builtin_amdgcn_mfma_f32_16x16x32_bf16(af[mi], bv[ni],
                                                              acc[mi][ni], 0, 0, 0);
    __builtin_amdgcn_s_setprio(0);

    if (kt + 1 < NT) stageB(cb ^ 1, kt + 1);
#pragma unroll
    for (int ni = 0; ni < 6; ++ni) bv[ni] = *(const bf16x8*)(pb + ni * 2048 + ch1);
#pragma unroll
    for (int mi = 0; mi < 4; ++mi) af[mi] = *(const bf16x8*)(pa + mi * 2048 + ch1);
    asm volatile("s_waitcnt lgkmcnt(0)" ::: "memory");
    __builtin_amdgcn_sched_barrier(0);
    __builtin_amdgcn_s_setprio(1);
#pragma unroll
    for (int mi = 0; mi < 4; ++mi)
#pragma unroll
      for (int ni = 0; ni < 6; ++ni)
        acc[mi][ni] = __builtin_amdgcn_mfma_f32_16x16x32_bf16(af[mi], bv[ni],
                                                              acc[mi][ni], 0, 0, 0);
    __builtin_amdgcn_s_setprio(0);

    if (kt + 1 < NT) {
      asm volatile("s_waitcnt vmcnt(0)" ::: "memory");
      __builtin_amdgcn_s_barrier();
    }
  }

  const int rq = lane >> 4;
#pragma unroll
  for (int ni = 0; ni < 6; ++ni) {
    int n = nbase + wc * 96 + ni * 16 + fr;
    float bb = bias[n];
#pragma unroll
    for (int mi = 0; mi < 4; ++mi) {
      int mrow = mbase + wr * 64 + mi * 16 + rq * 4;
      f32x4 v = acc[mi][ni];
#pragma unroll
      for (int j = 0; j < 4; ++j) C[(size_t)(mrow + j) * N + n] = v[j] + bb;
    }
  }
}

extern "C" void kernel_launch(void* const* d_in, const int* in_sizes, int n_in,
                              void* d_out, int out_size, void* d_ws, size_t ws_size,
                              hipStream_t stream) {
  const float* x = (const float*)d_in[0];     // (128,3,224,224) f32
  const float* W = (const float*)d_in[1];     // (768,3,16,16)  f32
  const float* bias = (const float*)d_in[2];  // (768,)         f32
  float* out = (float*)d_out;                 // (128,196,768)  f32

  unsigned short* A = (unsigned short*)d_ws;                         // 25088*768 bf16
  unsigned short* Wb = (unsigned short*)((char*)d_ws + 38535168);    // 589824 bf16
  unsigned short* sc = (unsigned short*)((char*)d_ws + 39714816);    // 384*112*112 bf16

  convw_kernel<<<576, 256, 0, stream>>>(W, Wb);
  dwt1_kernel<<<2352, 256, 0, stream>>>(x, A, sc);
  dwt2_kernel<<<588, 256, 0, stream>>>(sc, A);
  gemm_kernel<<<784, 256, 0, stream>>>(A, Wb, bias, out);
}

// Round 15
// 62.796 us; speedup vs baseline: 1.1504x; 1.1504x over previous
//
#include <hip/hip_runtime.h>
#include <stdint.h>

typedef __attribute__((ext_vector_type(8))) __bf16 bf16x8;
typedef __attribute__((ext_vector_type(4))) float f32x4;

__device__ __forceinline__ unsigned short f2bf(float f) {
  union { float f; unsigned int u; } v; v.f = f;
  unsigned int u = v.u;
  return (unsigned short)((u + 0x7fffu + ((u >> 16) & 1u)) >> 16);
}

__device__ __forceinline__ void async_copy16(const void* g, void* s) {
  __builtin_amdgcn_global_load_lds(
      (__attribute__((address_space(1))) void*)const_cast<void*>(g),
      (__attribute__((address_space(3))) void*)s,
      16, 0, 0);
}

#define HAAR(a, bb, cc, dd, oA, oH, oV, oD)                                    \
  oA = 0.5f * ((a + bb) + (cc + dd));                                          \
  oH = 0.5f * ((a + bb) - (cc + dd));                                          \
  oV = 0.5f * ((a - bb) + (cc - dd));                                          \
  oD = 0.5f * ((a - bb) - (cc - dd));

// ---- fused pre-kernel: blocks [0,576) = W fp32->bf16; [576,5280) = DWT ---
// convw: W (768,3,16,16) f32 -> Wb bf16 (already [N=768][K=768] row-major).
// dwt: 2-level Haar, 1 thread per 4x4 input block, writes bf16 A in the
// patch-flattened layout A[b*196+ph*14+pw][c*256+y16*16+x16].
__global__ __launch_bounds__(256) void pre_kernel(const float* __restrict__ x,
                                                  const float* __restrict__ W,
                                                  unsigned short* __restrict__ A,
                                                  unsigned short* __restrict__ Wb) {
  if (blockIdx.x < 576) {
    int i = blockIdx.x * 256 + threadIdx.x;  // 147456 threads x 4 floats
    float4 v = ((const float4*)W)[i];
    uint2 o;
    o.x = (unsigned int)f2bf(v.x) | ((unsigned int)f2bf(v.y) << 16);
    o.y = (unsigned int)f2bf(v.z) | ((unsigned int)f2bf(v.w) << 16);
    ((uint2*)Wb)[i] = o;
    return;
  }

  int tid = (blockIdx.x - 576) * 256 + threadIdx.x;  // 128*3*56*56 = 1204224
  int J = tid % 56;
  int t = tid / 56;
  int I = t % 56;
  t /= 56;  // t = b*3 + c
  int c = t % 3;
  int b = t / 3;

  const float* xp = x + (((size_t)t * 224 + 4 * I) * 224 + 4 * J);
  float4 r0 = *(const float4*)(xp);
  float4 r1 = *(const float4*)(xp + 224);
  float4 r2 = *(const float4*)(xp + 448);
  float4 r3 = *(const float4*)(xp + 672);

  float A1[2][2], H1[2][2], V1[2][2], D1[2][2];
  HAAR(r0.x, r0.y, r1.x, r1.y, A1[0][0], H1[0][0], V1[0][0], D1[0][0]);
  HAAR(r0.z, r0.w, r1.z, r1.w, A1[0][1], H1[0][1], V1[0][1], D1[0][1]);
  HAAR(r2.x, r2.y, r3.x, r3.y, A1[1][0], H1[1][0], V1[1][0], D1[1][0]);
  HAAR(r2.z, r2.w, r3.z, r3.w, A1[1][1], H1[1][1], V1[1][1], D1[1][1]);

  auto aidx = [&](int y, int xx) -> size_t {
    int mrow = b * 196 + (y >> 4) * 14 + (xx >> 4);
    int k = c * 256 + (y & 15) * 16 + (xx & 15);
    return (size_t)mrow * 768 + (size_t)k;
  };
  auto store2 = [&](int y, int xx, float v0, float v1) {
    unsigned int p = (unsigned int)f2bf(v0) | ((unsigned int)f2bf(v1) << 16);
    *(unsigned int*)(A + aidx(y, xx)) = p;  // xx even -> 4B aligned, same patch
  };

  int y0 = 2 * I, x0 = 2 * J;
  store2(y0,           112 + x0, H1[0][0], H1[0][1]);
  store2(y0 + 1,       112 + x0, H1[1][0], H1[1][1]);
  store2(112 + y0,     x0,       V1[0][0], V1[0][1]);
  store2(112 + y0 + 1, x0,       V1[1][0], V1[1][1]);
  store2(112 + y0,     112 + x0, D1[0][0], D1[0][1]);
  store2(112 + y0 + 1, 112 + x0, D1[1][0], D1[1][1]);

  float vA2, vH2, vV2, vD2;
  HAAR(A1[0][0], A1[0][1], A1[1][0], A1[1][1], vA2, vH2, vV2, vD2);
  A[aidx(I,      J)]      = f2bf(vA2);
  A[aidx(I,      56 + J)] = f2bf(vH2);
  A[aidx(56 + I, J)]      = f2bf(vV2);
  A[aidx(56 + I, 56 + J)] = f2bf(vD2);
}

// --------- bf16 MFMA GEMM (r13 exact): 128x192, BK=64, dbuf, 4 waves ------
// M=25088, N=768, K=768. Per iter: {stageA(t+1) | kh0 reads -> lgkm ->
// setprio MFMA | stageB(t+1) | kh1 reads -> lgkm -> setprio MFMA |
// vmcnt(0)+barrier}. Race-free (stage after the barrier fencing readers).
// Row=128B=8 chunks; XOR swizzle P(row)=row&7. 784 = 8 XCDs x 98 bijective.
__global__ __launch_bounds__(256) void gemm_kernel(const unsigned short* __restrict__ A,
                                                   const unsigned short* __restrict__ Bt,
                                                   const float* __restrict__ bias,
                                                   float* __restrict__ C) {
  constexpr int K = 768, N = 768;
  constexpr int NT = 12;  // K / 64
  __shared__ unsigned short As[2][128 * 64];  // 16 KB per buffer
  __shared__ unsigned short Bs[2][192 * 64];  // 24 KB per buffer

  const int orig = blockIdx.x;
  const int tile = (orig & 7) * 98 + (orig >> 3);
  const int bm = tile >> 2, bn = tile & 3;
  const int mbase = bm * 128, nbase = bn * 192;

  const int tid = threadIdx.x;
  const int lane = tid & 63;
  const int wave = tid >> 6;
  const int wr = wave >> 1, wc = wave & 1;  // wave tile 64x96

  f32x4 acc[4][6] = {};

  const int srow = wave * 8 + (lane >> 3);
  const int kcs = (lane & 7) ^ ((lane >> 3) & 7);
  const unsigned short* gA[4];
  const unsigned short* gB[6];
#pragma unroll
  for (int i = 0; i < 4; ++i) gA[i] = A + (size_t)(mbase + i * 32 + srow) * K + kcs * 8;
#pragma unroll
  for (int j = 0; j < 6; ++j) gB[j] = Bt + (size_t)(nbase + j * 32 + srow) * K + kcs * 8;

  auto stageA = [&](int buf, int kt) {
    char* sa = (char*)As + buf * 16384 + wave * 1024;
    const int ko = kt * 64;
#pragma unroll
    for (int i = 0; i < 4; ++i) async_copy16(gA[i] + ko, sa + i * 4096);
  };
  auto stageB = [&](int buf, int kt) {
    char* sb = (char*)Bs + buf * 24576 + wave * 1024;
    const int ko = kt * 64;
#pragma unroll
    for (int j = 0; j < 6; ++j) async_copy16(gB[j] + ko, sb + j * 4096);
  };

  const int fr = lane & 15;
  const int kq = lane >> 4;
  const int ch0 = ((0 * 4 + kq) ^ (fr & 7)) * 16;
  const int ch1 = ((1 * 4 + kq) ^ (fr & 7)) * 16;

  stageA(0, 0);
  stageB(0, 0);
  asm volatile("s_waitcnt vmcnt(0)" ::: "memory");
  __builtin_amdgcn_s_barrier();

#pragma unroll
  for (int kt = 0; kt < NT; ++kt) {
    const int cb = kt & 1;
    const char* pa = (const char*)As + cb * 16384 + (wr * 64 + fr) * 128;
    const char* pb = (const char*)Bs + cb * 24576 + (wc * 96 + fr) * 128;
    bf16x8 af[4], bv[6];

    if (kt + 1 < NT) stageA(cb ^ 1, kt + 1);
#pragma unroll
    for (int ni = 0; ni < 6; ++ni) bv[ni] = *(const bf16x8*)(pb + ni * 2048 + ch0);
#pragma unroll
    for (int mi = 0; mi < 4; ++mi) af[mi] = *(const bf16x8*)(pa + mi * 2048 + ch0);
    asm volatile("s_waitcnt lgkmcnt(0)" ::: "memory");
    __builtin_amdgcn_sched_barrier(0);
    __builtin_amdgcn_s_setprio(1);
#pragma unroll
    for (int mi = 0; mi < 4; ++mi)
#pragma unroll
      for (int ni = 0; ni < 6; ++ni)
        acc[mi][ni] = __builtin_amdgcn_mfma_f32_16x16x32_bf16(af[mi], bv[ni],
                                                              acc[mi][ni], 0, 0, 0);
    __builtin_amdgcn_s_setprio(0);

    if (kt + 1 < NT) stageB(cb ^ 1, kt + 1);
#pragma unroll
    for (int ni = 0; ni < 6; ++ni) bv[ni] = *(const bf16x8*)(pb + ni * 2048 + ch1);
#pragma unroll
    for (int mi = 0; mi < 4; ++mi) af[mi] = *(const bf16x8*)(pa + mi * 2048 + ch1);
    asm volatile("s_waitcnt lgkmcnt(0)" ::: "memory");
    __builtin_amdgcn_sched_barrier(0);
    __builtin_amdgcn_s_setprio(1);
#pragma unroll
    for (int mi = 0; mi < 4; ++mi)
#pragma unroll
      for (int ni = 0; ni < 6; ++ni)
        acc[mi][ni] = __builtin_amdgcn_mfma_f32_16x16x32_bf16(af[mi], bv[ni],
                                                              acc[mi][ni], 0, 0, 0);
    __builtin_amdgcn_s_setprio(0);

    if (kt + 1 < NT) {
      asm volatile("s_waitcnt vmcnt(0)" ::: "memory");
      __builtin_amdgcn_s_barrier();
    }
  }

  const int rq = lane >> 4;
#pragma unroll
  for (int ni = 0; ni < 6; ++ni) {
    int n = nbase + wc * 96 + ni * 16 + fr;
    float bb = bias[n];
#pragma unroll
    for (int mi = 0; mi < 4; ++mi) {
      int mrow = mbase + wr * 64 + mi * 16 + rq * 4;
      f32x4 v = acc[mi][ni];
#pragma unroll
      for (int j = 0; j < 4; ++j) C[(size_t)(mrow + j) * N + n] = v[j] + bb;
    }
  }
}

extern "C" void kernel_launch(void* const* d_in, const int* in_sizes, int n_in,
                              void* d_out, int out_size, void* d_ws, size_t ws_size,
                              hipStream_t stream) {
  const float* x = (const float*)d_in[0];     // (128,3,224,224) f32
  const float* W = (const float*)d_in[1];     // (768,3,16,16)  f32
  const float* bias = (const float*)d_in[2];  // (768,)         f32
  float* out = (float*)d_out;                 // (128,196,768)  f32

  unsigned short* A = (unsigned short*)d_ws;                        // 25088*768 bf16
  unsigned short* Wb = (unsigned short*)((char*)d_ws + 38535168);   // 589824 bf16

  pre_kernel<<<5280, 256, 0, stream>>>(x, W, A, Wb);
  gemm_kernel<<<784, 256, 0, stream>>>(A, Wb, bias, out);
}

// Round 16
// 62.347 us; speedup vs baseline: 1.1586x; 1.0072x over previous
//
#include <hip/hip_runtime.h>
#include <stdint.h>

typedef __attribute__((ext_vector_type(8))) __bf16 bf16x8;
typedef __attribute__((ext_vector_type(4))) float f32x4;

__device__ __forceinline__ unsigned short f2bf(float f) {
  union { float f; unsigned int u; } v; v.f = f;
  unsigned int u = v.u;
  return (unsigned short)((u + 0x7fffu + ((u >> 16) & 1u)) >> 16);
}

__device__ __forceinline__ void async_copy16(const void* g, void* s) {
  __builtin_amdgcn_global_load_lds(
      (__attribute__((address_space(1))) void*)const_cast<void*>(g),
      (__attribute__((address_space(3))) void*)s,
      16, 0, 0);
}

#define HAAR(a, bb, cc, dd, oA, oH, oV, oD)                                    \
  oA = 0.5f * ((a + bb) + (cc + dd));                                          \
  oH = 0.5f * ((a + bb) - (cc + dd));                                          \
  oV = 0.5f * ((a - bb) + (cc - dd));                                          \
  oD = 0.5f * ((a - bb) - (cc - dd));

// ---- fused pre-kernel: blocks [0,576) = W fp32->bf16; [576,5280) = DWT ---
__global__ __launch_bounds__(256) void pre_kernel(const float* __restrict__ x,
                                                  const float* __restrict__ W,
                                                  unsigned short* __restrict__ A,
                                                  unsigned short* __restrict__ Wb) {
  if (blockIdx.x < 576) {
    int i = blockIdx.x * 256 + threadIdx.x;  // 147456 threads x 4 floats
    float4 v = ((const float4*)W)[i];
    uint2 o;
    o.x = (unsigned int)f2bf(v.x) | ((unsigned int)f2bf(v.y) << 16);
    o.y = (unsigned int)f2bf(v.z) | ((unsigned int)f2bf(v.w) << 16);
    ((uint2*)Wb)[i] = o;
    return;
  }

  int tid = (blockIdx.x - 576) * 256 + threadIdx.x;  // 128*3*56*56 = 1204224
  int J = tid % 56;
  int t = tid / 56;
  int I = t % 56;
  t /= 56;  // t = b*3 + c
  int c = t % 3;
  int b = t / 3;

  const float* xp = x + (((size_t)t * 224 + 4 * I) * 224 + 4 * J);
  float4 r0 = *(const float4*)(xp);
  float4 r1 = *(const float4*)(xp + 224);
  float4 r2 = *(const float4*)(xp + 448);
  float4 r3 = *(const float4*)(xp + 672);

  float A1[2][2], H1[2][2], V1[2][2], D1[2][2];
  HAAR(r0.x, r0.y, r1.x, r1.y, A1[0][0], H1[0][0], V1[0][0], D1[0][0]);
  HAAR(r0.z, r0.w, r1.z, r1.w, A1[0][1], H1[0][1], V1[0][1], D1[0][1]);
  HAAR(r2.x, r2.y, r3.x, r3.y, A1[1][0], H1[1][0], V1[1][0], D1[1][0]);
  HAAR(r2.z, r2.w, r3.z, r3.w, A1[1][1], H1[1][1], V1[1][1], D1[1][1]);

  auto aidx = [&](int y, int xx) -> size_t {
    int mrow = b * 196 + (y >> 4) * 14 + (xx >> 4);
    int k = c * 256 + (y & 15) * 16 + (xx & 15);
    return (size_t)mrow * 768 + (size_t)k;
  };
  auto store2 = [&](int y, int xx, float v0, float v1) {
    unsigned int p = (unsigned int)f2bf(v0) | ((unsigned int)f2bf(v1) << 16);
    *(unsigned int*)(A + aidx(y, xx)) = p;  // xx even -> 4B aligned, same patch
  };

  int y0 = 2 * I, x0 = 2 * J;
  store2(y0,           112 + x0, H1[0][0], H1[0][1]);
  store2(y0 + 1,       112 + x0, H1[1][0], H1[1][1]);
  store2(112 + y0,     x0,       V1[0][0], V1[0][1]);
  store2(112 + y0 + 1, x0,       V1[1][0], V1[1][1]);
  store2(112 + y0,     112 + x0, D1[0][0], D1[0][1]);
  store2(112 + y0 + 1, 112 + x0, D1[1][0], D1[1][1]);

  float vA2, vH2, vV2, vD2;
  HAAR(A1[0][0], A1[0][1], A1[1][0], A1[1][1], vA2, vH2, vV2, vD2);
  A[aidx(I,      J)]      = f2bf(vA2);
  A[aidx(I,      56 + J)] = f2bf(vH2);
  A[aidx(56 + I, J)]      = f2bf(vV2);
  A[aidx(56 + I, 56 + J)] = f2bf(vD2);
}

// --------- bf16 MFMA GEMM: C[M][N] = A[M][K] * Bt[N][K]^T + bias -----------
// M=25088, N=768, K=768. 128x192 block, BK=64, dbuf, 4 waves of 64x96.
// vs r13: both stages issued at iter TOP (full-iter load lead -> iter-end
// vmcnt(0) drain ~free); no mid-iter manual lgkm/sched_barrier (compiler
// emits incremental lgkmcnt per MFMA operand); no setprio (T5 null on
// 2-phase). Iter end: lgkmcnt(0) [read/overwrite fence] + vmcnt(0) + barrier.
__global__ __launch_bounds__(256) void gemm_kernel(const unsigned short* __restrict__ A,
                                                   const unsigned short* __restrict__ Bt,
                                                   const float* __restrict__ bias,
                                                   float* __restrict__ C) {
  constexpr int K = 768, N = 768;
  constexpr int NT = 12;  // K / 64
  __shared__ unsigned short As[2][128 * 64];  // 16 KB per buffer
  __shared__ unsigned short Bs[2][192 * 64];  // 24 KB per buffer

  const int orig = blockIdx.x;
  const int tile = (orig & 7) * 98 + (orig >> 3);
  const int bm = tile >> 2, bn = tile & 3;
  const int mbase = bm * 128, nbase = bn * 192;

  const int tid = threadIdx.x;
  const int lane = tid & 63;
  const int wave = tid >> 6;
  const int wr = wave >> 1, wc = wave & 1;  // wave tile 64x96

  f32x4 acc[4][6] = {};

  const int srow = wave * 8 + (lane >> 3);
  const int kcs = (lane & 7) ^ ((lane >> 3) & 7);
  const unsigned short* gA[4];
  const unsigned short* gB[6];
#pragma unroll
  for (int i = 0; i < 4; ++i) gA[i] = A + (size_t)(mbase + i * 32 + srow) * K + kcs * 8;
#pragma unroll
  for (int j = 0; j < 6; ++j) gB[j] = Bt + (size_t)(nbase + j * 32 + srow) * K + kcs * 8;

  auto stage = [&](int buf, int kt) {
    char* sa = (char*)As + buf * 16384 + wave * 1024;
    char* sb = (char*)Bs + buf * 24576 + wave * 1024;
    const int ko = kt * 64;
#pragma unroll
    for (int i = 0; i < 4; ++i) async_copy16(gA[i] + ko, sa + i * 4096);
#pragma unroll
    for (int j = 0; j < 6; ++j) async_copy16(gB[j] + ko, sb + j * 4096);
  };

  const int fr = lane & 15;
  const int kq = lane >> 4;
  const int ch0 = ((0 * 4 + kq) ^ (fr & 7)) * 16;
  const int ch1 = ((1 * 4 + kq) ^ (fr & 7)) * 16;

  stage(0, 0);
  asm volatile("s_waitcnt vmcnt(0)" ::: "memory");
  __builtin_amdgcn_s_barrier();

#pragma unroll
  for (int kt = 0; kt < NT; ++kt) {
    const int cb = kt & 1;
    // stage next tile FIRST: loads get the whole iteration to land.
    // Race-free: writes buf[cb^1], whose readers (iter kt-1) were
    // lgkm-fenced before the barrier we just crossed.
    if (kt + 1 < NT) stage(cb ^ 1, kt + 1);

    const char* pa = (const char*)As + cb * 16384 + (wr * 64 + fr) * 128;
    const char* pb = (const char*)Bs + cb * 24576 + (wc * 96 + fr) * 128;
    bf16x8 af[4], bv[6];

    // k-half 0 (compiler inserts incremental lgkmcnt before each MFMA)
#pragma unroll
    for (int ni = 0; ni < 6; ++ni) bv[ni] = *(const bf16x8*)(pb + ni * 2048 + ch0);
#pragma unroll
    for (int mi = 0; mi < 4; ++mi) af[mi] = *(const bf16x8*)(pa + mi * 2048 + ch0);
#pragma unroll
    for (int mi = 0; mi < 4; ++mi)
#pragma unroll
      for (int ni = 0; ni < 6; ++ni)
        acc[mi][ni] = __builtin_amdgcn_mfma_f32_16x16x32_bf16(af[mi], bv[ni],
                                                              acc[mi][ni], 0, 0, 0);
    // k-half 1
#pragma unroll
    for (int ni = 0; ni < 6; ++ni) bv[ni] = *(const bf16x8*)(pb + ni * 2048 + ch1);
#pragma unroll
    for (int mi = 0; mi < 4; ++mi) af[mi] = *(const bf16x8*)(pa + mi * 2048 + ch1);
#pragma unroll
    for (int mi = 0; mi < 4; ++mi)
#pragma unroll
      for (int ni = 0; ni < 6; ++ni)
        acc[mi][ni] = __builtin_amdgcn_mfma_f32_16x16x32_bf16(af[mi], bv[ni],
                                                              acc[mi][ni], 0, 0, 0);

    if (kt + 1 < NT) {
      asm volatile("s_waitcnt lgkmcnt(0)" ::: "memory");  // my reads of buf[cb] done
      asm volatile("s_waitcnt vmcnt(0)" ::: "memory");    // my stages landed
      __builtin_amdgcn_s_barrier();                       // all waves ready
    }
  }

  const int rq = lane >> 4;
#pragma unroll
  for (int ni = 0; ni < 6; ++ni) {
    int n = nbase + wc * 96 + ni * 16 + fr;
    float bb = bias[n];
#pragma unroll
    for (int mi = 0; mi < 4; ++mi) {
      int mrow = mbase + wr * 64 + mi * 16 + rq * 4;
      f32x4 v = acc[mi][ni];
#pragma unroll
      for (int j = 0; j < 4; ++j) C[(size_t)(mrow + j) * N + n] = v[j] + bb;
    }
  }
}

extern "C" void kernel_launch(void* const* d_in, const int* in_sizes, int n_in,
                              void* d_out, int out_size, void* d_ws, size_t ws_size,
                              hipStream_t stream) {
  const float* x = (const float*)d_in[0];     // (128,3,224,224) f32
  const float* W = (const float*)d_in[1];     // (768,3,16,16)  f32
  const float* bias = (const float*)d_in[2];  // (768,)         f32
  float* out = (float*)d_out;                 // (128,196,768)  f32

  unsigned short* A = (unsigned short*)d_ws;                        // 25088*768 bf16
  unsigned short* Wb = (unsigned short*)((char*)d_ws + 38535168);   // 589824 bf16

  pre_kernel<<<5280, 256, 0, stream>>>(x, W, A, Wb);
  gemm_kernel<<<784, 256, 0, stream>>>(A, Wb, bias, out);
}